// Round 12
// baseline (849.680 us; speedup 1.0000x reference)
//
#include <hip/hip_runtime.h>
#include <hip/hip_fp16.h>

#define BLK 256
#define BBLK 512             // k_bin block
#define ABLK 512             // fused agg block: 256 lane-pairs
#define DBLK 512             // ldeg_t1 block (dual LDS counter banks)
#define NBK 782              // dst buckets of 256 nodes (782*256 >= 200000)
#define BW 256               // nodes per bucket (dl fits 8 bits)
#define NK2 512              // sort keys: (dl<<1) | src_half
#define NPAD (NBK * BW)      // padded node count (200192)
#define HALF (NPAD / 2)      // src-half threshold: each hs1 half = 3.2 MB (L2-fits)
#define CAP 8832             // edges/chunk (max bucket ~8500; LDS 39.7 KB -> 4 blk/CU)
#define NCH 3                // max chunks per bucket tracked in doff (fallback only)
#define CHUNK 6144           // edges per binning block -> 1042 blocks

// ---------- bucket build ----------

// per-block histogram -> blockhist row (persisted) + global bucket counts.
__global__ void k_hist(const int* __restrict__ dst, int e, int* __restrict__ gcnt,
                       int* __restrict__ blockhist) {
  __shared__ int h[NBK];
  for (int i = threadIdx.x; i < NBK; i += BLK) h[i] = 0;
  __syncthreads();
  int base = blockIdx.x * CHUNK;
  int m = min(CHUNK, e - base);
  int m4 = m >> 2;
  const int4* d4 = (const int4*)(dst + base);
  for (int k = threadIdx.x; k < m4; k += BLK) {
    int4 vv = d4[k];
    atomicAdd(&h[vv.x >> 8], 1);
    atomicAdd(&h[vv.y >> 8], 1);
    atomicAdd(&h[vv.z >> 8], 1);
    atomicAdd(&h[vv.w >> 8], 1);
  }
  for (int k = (m4 << 2) + threadIdx.x; k < m; k += BLK)
    atomicAdd(&h[dst[base + k] >> 8], 1);
  __syncthreads();
  int* row = blockhist + (size_t)blockIdx.x * NBK;
  int sft = (blockIdx.x * 193) % NBK;   // stagger to decorrelate gcnt atomics
  for (int bb = threadIdx.x; bb < NBK; bb += BLK) {
    int b = bb + sft; if (b >= NBK) b -= NBK;
    int c = h[b];
    row[b] = c;
    if (c) atomicAdd(&gcnt[b], c);
  }
}

// exclusive scan of gcnt[NBK] -> gbase[NBK+1]; init gcur. single block, 1024 thr.
__global__ void k_scan(const int* __restrict__ gcnt, int* __restrict__ gbase,
                       int* __restrict__ gcur, int e) {
  __shared__ int s[1024];
  int t = threadIdx.x;
  int v = (t < NBK) ? gcnt[t] : 0;
  s[t] = v;
  __syncthreads();
  for (int d = 1; d < 1024; d <<= 1) {
    int u = (t >= d) ? s[t - d] : 0;
    __syncthreads();
    s[t] += u;
    __syncthreads();
  }
  if (t < NBK) { int ex = s[t] - v; gbase[t] = ex; gcur[t] = ex; }
  if (t == 0) gbase[NBK] = e;
}

// bin edges: load saved histogram, LDS counting-sort, coalesced write-out with
// direct pos->bucket lookup. Wave-shuffle scan (2 barriers).
__global__ void __launch_bounds__(BBLK) k_bin(const int* __restrict__ src,
                                              const int* __restrict__ dst, int e,
                                              int* __restrict__ gcur,
                                              const int* __restrict__ blockhist,
                                              unsigned* __restrict__ binned) {
  __shared__ int lcnt[NBK];        // histogram, then reused as scatter cursor
  __shared__ int loff[NBK + 1];
  __shared__ int lbase[NBK];
  __shared__ int wsum[8];
  __shared__ unsigned sorted[CHUNK];        // 24 KB
  __shared__ unsigned short bkt16[CHUNK];   // 12 KB
  int t = threadIdx.x;
  int base = blockIdx.x * CHUNK;
  int m = min(CHUNK, e - base);

  const int* row = blockhist + (size_t)blockIdx.x * NBK;
  for (int i = t; i < NBK; i += BBLK) lcnt[i] = row[i];
  __syncthreads();
  int b0 = 2 * t;
  int s0 = (b0 + 0 < NBK) ? lcnt[b0 + 0] : 0;
  int s1 = (b0 + 1 < NBK) ? lcnt[b0 + 1] : 0;
  int tsum = s0 + s1;
  // wave-shuffle inclusive scan of tsum over 512 threads
  int lane = t & 63, wid = t >> 6;
  int incl = tsum;
#pragma unroll
  for (int d = 1; d < 64; d <<= 1) {
    int u = __shfl_up(incl, d);
    if (lane >= d) incl += u;
  }
  if (lane == 63) wsum[wid] = incl;
  __syncthreads();
  if (t == 0) {
    int run = 0;
#pragma unroll
    for (int i = 0; i < 8; i++) { int tv = wsum[i]; wsum[i] = run; run += tv; }
  }
  __syncthreads();
  int ex = incl - tsum + wsum[wid];
  if (b0 + 0 < NBK) loff[b0 + 0] = ex;
  if (b0 + 1 < NBK) loff[b0 + 1] = ex + s0;
  if (t == 0) loff[NBK] = m;
  __syncthreads();
  int sft = (blockIdx.x * 193) % NBK;   // stagger to decorrelate gcur atomics
  for (int bb = t; bb < NBK; bb += BBLK) {
    int b = bb + sft; if (b >= NBK) b -= NBK;
    int c = lcnt[b];
    lbase[b] = c ? atomicAdd(&gcur[b], c) : 0;
  }
  __syncthreads();
  for (int b = t; b < NBK; b += BBLK) lcnt[b] = loff[b];
  __syncthreads();
  for (int k = t; k < m; k += BBLK) {
    int d = dst[base + k];
    int b = d >> 8;
    int dl = d & 255;
    int pos = atomicAdd(&lcnt[b], 1);
    sorted[pos] = (unsigned)src[base + k] | ((unsigned)dl << 18);
    bkt16[pos] = (unsigned short)b;
  }
  __syncthreads();
  for (int i = t; i < m; i += BBLK) {
    int b = bkt16[i];
    binned[lbase[b] + (i - loff[b])] = sorted[i];
  }
}

// fused: per-bucket 512-key counts (key = dl<<1 | src_half) -> deg2 + dinv ->
// hs1 = fp16((x@W1)*dinv), interleaved 32B rows. 4-deep unrolled count loop.
// NOTE: deg2 row is written for ALL t < NK2 in every bucket (incl. tail).
__global__ void __launch_bounds__(DBLK) k_ldeg_t1(const unsigned* __restrict__ binned,
                                                  const int* __restrict__ gbase,
                                                  const float* __restrict__ x,
                                                  const float* __restrict__ W1,
                                                  int* __restrict__ deg2,
                                                  float* __restrict__ dinv,
                                                  __half* __restrict__ hs1, int n) {
  __shared__ int cnt[2][NK2];      // 4 KB, dual banks to halve atomic contention
  __shared__ float w[160];
  int t = threadIdx.x;
  cnt[0][t] = 0;
  cnt[1][t] = 0;
  if (t < 160) w[t] = W1[t];
  __syncthreads();
  int b = blockIdx.x;
  int p0 = gbase[b], p1 = gbase[b + 1];
  int h = t >> 8;
#define KEYOF(u) ((int)(((u) >> 18) << 1) | (int)(((u) & 0x3FFFFu) >= (unsigned)HALF))
  int p = p0 + t;
  for (; p + 3 * DBLK < p1; p += 4 * DBLK) {
    unsigned u0 = binned[p];
    unsigned u1 = binned[p + DBLK];
    unsigned u2 = binned[p + 2 * DBLK];
    unsigned u3 = binned[p + 3 * DBLK];
    atomicAdd(&cnt[h][KEYOF(u0)], 1);
    atomicAdd(&cnt[h][KEYOF(u1)], 1);
    atomicAdd(&cnt[h][KEYOF(u2)], 1);
    atomicAdd(&cnt[h][KEYOF(u3)], 1);
  }
  for (; p < p1; p += DBLK) {
    unsigned u = binned[p];
    atomicAdd(&cnt[h][KEYOF(u)], 1);
  }
#undef KEYOF
  __syncthreads();
  deg2[(size_t)b * NK2 + t] = cnt[0][t] + cnt[1][t];   // always: full row
  if (t >= BW) return;
  int v = b * BW + t;
  if (v >= n) return;
  int dg = cnt[0][2 * t] + cnt[0][2 * t + 1] + cnt[1][2 * t] + cnt[1][2 * t + 1];
  float di = rsqrtf((float)dg + 1.0f);
  dinv[v] = di;
  float xi[10];
#pragma unroll
  for (int k = 0; k < 10; k++) xi[k] = x[(size_t)v * 10 + k];
  __half2 hv[8];
#pragma unroll
  for (int j = 0; j < 8; j++) {
    float acc0 = 0.f, acc1 = 0.f;
#pragma unroll
    for (int k = 0; k < 10; k++) {
      acc0 = fmaf(xi[k], w[k * 16 + 2 * j], acc0);
      acc1 = fmaf(xi[k], w[k * 16 + 2 * j + 1], acc1);
    }
    hv[j] = __floats2half2_rn(acc0 * di, acc1 * di);
  }
  float4* o = (float4*)(hs1 + (size_t)v * 16);
  o[0] = *(float4*)&hv[0];
  o[1] = *(float4*)&hv[4];
}

// FUSED layers 1+2, plain launch + MANUAL device-scope grid barrier (graph-
// capturable, unlike hipLaunchCooperativeKernel — the round-11 failure).
// Residency proof: __launch_bounds__(512,8) -> <=64 VGPR -> 4 blk/CU by waves;
// LDS 39.7 KB -> 4 blk/CU; grid 782 <= 4*256=1024 slots => all blocks
// co-resident, spin cannot deadlock. Protocol: release fence -> t0 atomicAdd ->
// t0 acquire-spin -> syncthreads -> per-wave acquire fence -> read hs2.
__global__ void __launch_bounds__(ABLK, 8) k_aggf(unsigned* __restrict__ binned,
                                                  const int* __restrict__ gbase,
                                                  const int* __restrict__ deg2,
                                                  int* __restrict__ doff,
                                                  const __half* __restrict__ hs1,
                                                  const float* __restrict__ dinv,
                                                  const float* __restrict__ b1,
                                                  const float* __restrict__ W2,
                                                  const float* __restrict__ b2,
                                                  float* __restrict__ hs2,
                                                  float* __restrict__ out,
                                                  int* __restrict__ bar, int n) {
  __shared__ int cnt[NK2];          // counts -> scatter cursor
  __shared__ int off[NK2 + 1];
  __shared__ int sorted[CAP];       // 34.5 KB
  __shared__ int wsum[8];
  __shared__ float w2[32];
  __shared__ float sb1[16];
  int t = threadIdx.x;
  if (t < 32) w2[t] = W2[t];
  if (t >= 32 && t < 48) sb1[t - 32] = b1[t - 32];
  int bkt = blockIdx.x;
  int p0 = gbase[bkt], p1 = gbase[bkt + 1];
  const bool fast = (p1 - p0) <= CAP;   // single chunk: deg2 == per-chunk counts
  const int j = t >> 1;
  const int c = t & 1;
  const int lane = t & 63, wid = t >> 6;
  float acc[8];
#pragma unroll
  for (int q = 0; q < 8; q++) acc[q] = 0.f;

#define ACCR(R) { const __half2* h2_ = (const __half2*)&R; \
    float2 f0_ = __half22float2(h2_[0]); \
    float2 f1_ = __half22float2(h2_[1]); \
    float2 f2_ = __half22float2(h2_[2]); \
    float2 f3_ = __half22float2(h2_[3]); \
    acc[0] += f0_.x; acc[1] += f0_.y; acc[2] += f1_.x; acc[3] += f1_.y; \
    acc[4] += f2_.x; acc[5] += f2_.y; acc[6] += f3_.x; acc[7] += f3_.y; }

  int p = p0;
  int cidx = 0;
  while (p < p1) {
    int m = min(CAP, p1 - p);
    int myv;
    if (fast) {
      myv = deg2[(size_t)bkt * NK2 + t];
    } else {
      cnt[t] = 0;
      __syncthreads();
      for (int i = t; i < m; i += ABLK) {
        unsigned u = __builtin_nontemporal_load(&binned[p + i]);
        int key = (int)((u >> 18) << 1) | (int)((u & 0x3FFFFu) >= (unsigned)HALF);
        atomicAdd(&cnt[key], 1);
      }
      __syncthreads();
      myv = cnt[t];
    }
    // wave-shuffle exclusive scan of myv over 512 threads
    int incl = myv;
#pragma unroll
    for (int d = 1; d < 64; d <<= 1) {
      int u = __shfl_up(incl, d);
      if (lane >= d) incl += u;
    }
    if (lane == 63) wsum[wid] = incl;
    __syncthreads();
    if (t == 0) {
      int run = 0;
#pragma unroll
      for (int i = 0; i < 8; i++) { int tv = wsum[i]; wsum[i] = run; run += tv; }
    }
    __syncthreads();
    int ex = incl - myv + wsum[wid];
    off[t] = ex;
    if (t == NK2 - 1) off[NK2] = m;
    cnt[t] = ex;                    // scatter cursor
    __syncthreads();
    if (!fast && cidx < NCH && t <= BW)
      doff[((size_t)bkt * NCH + cidx) * (BW + 1) + t] = off[2 * t];
    for (int i = t; i < m; i += ABLK) {
      unsigned pk = __builtin_nontemporal_load(&binned[p + i]);
      int srcv = (int)(pk & 0x3FFFFu);
      int key = (int)((pk >> 18) << 1) | (int)(srcv >= HALF);
      int pos = atomicAdd(&cnt[key], 1);
      sorted[pos] = srcv;
    }
    __syncthreads();
    if (!fast) {
      // fallback only: persist dl-sorted srcs for the post-barrier chunk loop
      for (int i = t; i < m; i += ABLK)
        __builtin_nontemporal_store((unsigned)sorted[i], &binned[p + i]);
    }
    int iA0 = off[2 * j], iA1 = off[2 * j + 1], iB1 = off[2 * j + 2];
    // ---- phase A: src < HALF (hs1 lower 3.2 MB) ----
    int i = iA0;
    for (; i + 3 < iA1; i += 4) {
      int s0 = sorted[i + 0];
      int s1 = sorted[i + 1];
      int s2 = sorted[i + 2];
      int s3 = sorted[i + 3];
      float4 r0 = *(const float4*)(hs1 + (size_t)s0 * 16 + c * 8);
      float4 r1 = *(const float4*)(hs1 + (size_t)s1 * 16 + c * 8);
      float4 r2 = *(const float4*)(hs1 + (size_t)s2 * 16 + c * 8);
      float4 r3 = *(const float4*)(hs1 + (size_t)s3 * 16 + c * 8);
      ACCR(r0); ACCR(r1); ACCR(r2); ACCR(r3);
    }
    for (; i < iA1; i++) {
      float4 r = *(const float4*)(hs1 + (size_t)sorted[i] * 16 + c * 8);
      ACCR(r);
    }
    __syncthreads();   // phase alignment: block-wide working set = one half
    // ---- phase B: src >= HALF (hs1 upper 3.2 MB) ----
    for (; i + 3 < iB1; i += 4) {
      int s0 = sorted[i + 0];
      int s1 = sorted[i + 1];
      int s2 = sorted[i + 2];
      int s3 = sorted[i + 3];
      float4 r0 = *(const float4*)(hs1 + (size_t)s0 * 16 + c * 8);
      float4 r1 = *(const float4*)(hs1 + (size_t)s1 * 16 + c * 8);
      float4 r2 = *(const float4*)(hs1 + (size_t)s2 * 16 + c * 8);
      float4 r3 = *(const float4*)(hs1 + (size_t)s3 * 16 + c * 8);
      ACCR(r0); ACCR(r1); ACCR(r2); ACCR(r3);
    }
    for (; i < iB1; i++) {
      float4 r = *(const float4*)(hs1 + (size_t)sorted[i] * 16 + c * 8);
      ACCR(r);
    }
    __syncthreads();
    p += m;
    cidx++;
  }
#undef ACCR

  // ---- layer-1 epilogue: hs2[v] (both lanes keep the full h0/h1 and di) ----
  int v = bkt * BW + j;
  const bool own = (v < n);
  float di = 0.f, h0d = 0.f, h1d = 0.f;
  if (own) {
    di = dinv[v];
    float4 sf = *(const float4*)(hs1 + (size_t)v * 16 + c * 8);
    const __half2* sh = (const __half2*)&sf;
    float h0c = 0.f, h1c = 0.f;
#pragma unroll
    for (int q = 0; q < 4; q++) {
      float2 sv = __half22float2(sh[q]);
      int f0 = c * 8 + 2 * q;
      int f1 = f0 + 1;
      float a0 = fmaxf(fmaf(di, acc[2 * q + 0] + sv.x, sb1[f0]), 0.f);
      float a1 = fmaxf(fmaf(di, acc[2 * q + 1] + sv.y, sb1[f1]), 0.f);
      h0c = fmaf(a0, w2[f0 * 2 + 0], fmaf(a1, w2[f1 * 2 + 0], h0c));
      h1c = fmaf(a0, w2[f0 * 2 + 1], fmaf(a1, w2[f1 * 2 + 1], h1c));
    }
    float h0 = h0c + __shfl_xor(h0c, 1);
    float h1 = h1c + __shfl_xor(h1c, 1);
    h0d = h0 * di;
    h1d = h1 * di;
    if (c == 0) {
      hs2[(size_t)v * 2 + 0] = h0d;
      hs2[(size_t)v * 2 + 1] = h1d;
    }
  }

  // ---- manual grid barrier (all 782 blocks co-resident by construction) ----
  __threadfence();                  // release: hs2 writes visible device-wide
  __syncthreads();
  if (t == 0) {
    atomicAdd(bar, 1);
    while (__hip_atomic_load(bar, __ATOMIC_ACQUIRE, __HIP_MEMORY_SCOPE_AGENT)
           < (int)gridDim.x)
      __builtin_amdgcn_s_sleep(8);
  }
  __syncthreads();
  __threadfence();                  // acquire: invalidate stale cached hs2

  // ---- layer 2: gather hs2 over this dst's dl-segment (LDS-resident) ----
  float a0 = 0.f, a1 = 0.f;
  if (fast) {
    int i0 = off[2 * j], i1 = off[2 * j + 2];
    int i = i0 + c;
    for (; i + 6 < i1; i += 8) {
      int s0 = sorted[i + 0];
      int s1 = sorted[i + 2];
      int s2 = sorted[i + 4];
      int s3 = sorted[i + 6];
      float2 m0 = *(const float2*)(hs2 + (size_t)s0 * 2);
      float2 m1 = *(const float2*)(hs2 + (size_t)s1 * 2);
      float2 m2 = *(const float2*)(hs2 + (size_t)s2 * 2);
      float2 m3 = *(const float2*)(hs2 + (size_t)s3 * 2);
      a0 += m0.x + m1.x + m2.x + m3.x;
      a1 += m0.y + m1.y + m2.y + m3.y;
    }
    for (; i < i1; i += 2) {
      float2 m = *(const float2*)(hs2 + (size_t)sorted[i] * 2);
      a0 += m.x;
      a1 += m.y;
    }
  } else {
    int cidx2 = 0;
    for (int pp = p0; pp < p1; pp += CAP, cidx2++) {
      const int* row = doff + ((size_t)bkt * NCH + cidx2) * (BW + 1);
      int i0 = row[j], i1 = row[j + 1];
      const unsigned* bp = binned + pp;
      int i = i0 + c;
      for (; i + 6 < i1; i += 8) {
        int s0 = bp[i + 0];
        int s1 = bp[i + 2];
        int s2 = bp[i + 4];
        int s3 = bp[i + 6];
        float2 m0 = *(const float2*)(hs2 + (size_t)s0 * 2);
        float2 m1 = *(const float2*)(hs2 + (size_t)s1 * 2);
        float2 m2 = *(const float2*)(hs2 + (size_t)s2 * 2);
        float2 m3 = *(const float2*)(hs2 + (size_t)s3 * 2);
        a0 += m0.x + m1.x + m2.x + m3.x;
        a1 += m0.y + m1.y + m2.y + m3.y;
      }
      for (; i < i1; i += 2) {
        float2 m = *(const float2*)(hs2 + (size_t)bp[i] * 2);
        a0 += m.x;
        a1 += m.y;
      }
    }
  }
  a0 += __shfl_xor(a0, 1);
  a1 += __shfl_xor(a1, 1);
  if (c == 0 && own) {
    out[(size_t)v * 2 + 0] = fmaf(di, a0 + h0d, b2[0]);
    out[(size_t)v * 2 + 1] = fmaf(di, a1 + h1d, b2[1]);
  }
}

extern "C" void kernel_launch(void* const* d_in, const int* in_sizes, int n_in,
                              void* d_out, int out_size, void* d_ws, size_t ws_size,
                              hipStream_t stream) {
  const float* x  = (const float*)d_in[0];
  const int*   ei = (const int*)d_in[1];
  const float* W1 = (const float*)d_in[2];
  const float* b1 = (const float*)d_in[3];
  const float* W2 = (const float*)d_in[4];
  const float* b2 = (const float*)d_in[5];
  float* out = (float*)d_out;

  const int n = in_sizes[0] / 10;   // 200000
  const int e = in_sizes[1] / 2;    // 6400000
  const int* src = ei;
  const int* dst = ei + e;

  int gC = (e + CHUNK - 1) / CHUNK;   // 1042 binning blocks

  // workspace layout (~42 MB). bar sits right after gcnt: one memset zeroes both.
  char* ws = (char*)d_ws;
  int*      gcnt      = (int*)ws;      ws += (size_t)NBK * 4;
  int*      bar       = (int*)ws;      ws += 4;
  int*      gbase     = (int*)ws;      ws += ((size_t)NBK + 1) * 4;
  int*      gcur      = (int*)ws;      ws += (size_t)NBK * 4;
  int*      deg2      = (int*)ws;      ws += (size_t)NBK * NK2 * 4;
  int*      doff      = (int*)ws;      ws += (size_t)NBK * NCH * (BW + 1) * 4;
  int*      blockhist = (int*)ws;      ws += (size_t)gC * NBK * 4;
  unsigned* binned    = (unsigned*)ws; ws += (size_t)e * 4;
  float*    dinv      = (float*)ws;    ws += (size_t)n * 4;
  __half*   hs1       = (__half*)ws;   ws += (size_t)NPAD * 16 * 2;
  float*    hs2       = (float*)ws;    ws += (size_t)n * 2 * 4;

  hipMemsetAsync(gcnt, 0, ((size_t)NBK + 1) * 4, stream);
  k_hist<<<gC, BLK, 0, stream>>>(dst, e, gcnt, blockhist);
  k_scan<<<1, 1024, 0, stream>>>(gcnt, gbase, gcur, e);
  k_bin<<<gC, BBLK, 0, stream>>>(src, dst, e, gcur, blockhist, binned);
  k_ldeg_t1<<<NBK, DBLK, 0, stream>>>(binned, gbase, x, W1, deg2, dinv, hs1, n);
  k_aggf<<<NBK, ABLK, 0, stream>>>(binned, gbase, deg2, doff, hs1, dinv, b1, W2,
                                   b2, hs2, out, bar, n);
}

// Round 13
// 605.300 us; speedup vs baseline: 1.4037x; 1.4037x over previous
//
#include <hip/hip_runtime.h>
#include <hip/hip_fp16.h>

#define BLK 256
#define BBLK 512             // k_bin block
#define ABLK 512             // fused agg block: 256 lane-pairs
#define DBLK 512             // ldeg_t1 block (dual LDS counter banks)
#define NBK 782              // dst buckets of 256 nodes (782*256 >= 200000)
#define BW 256               // nodes per bucket (dl fits 8 bits)
#define NK2 512              // sort keys: (dl<<1) | src_half
#define NPAD (NBK * BW)      // padded node count (200192)
#define HALF (NPAD / 2)      // src-half threshold: each hs1 half = 3.2 MB (L2-fits)
#define CAP 8832             // edges/chunk (max bucket ~8500; LDS 39.7 KB -> 4 blk/CU)
#define NCH 3                // max chunks per bucket tracked in doff (fallback only)
#define CHUNK 6144           // edges per binning block -> 1042 blocks

// ---------- bucket build ----------

// per-block histogram -> blockhist row (persisted) + global bucket counts.
__global__ void k_hist(const int* __restrict__ dst, int e, int* __restrict__ gcnt,
                       int* __restrict__ blockhist) {
  __shared__ int h[NBK];
  for (int i = threadIdx.x; i < NBK; i += BLK) h[i] = 0;
  __syncthreads();
  int base = blockIdx.x * CHUNK;
  int m = min(CHUNK, e - base);
  int m4 = m >> 2;
  const int4* d4 = (const int4*)(dst + base);
  for (int k = threadIdx.x; k < m4; k += BLK) {
    int4 vv = d4[k];
    atomicAdd(&h[vv.x >> 8], 1);
    atomicAdd(&h[vv.y >> 8], 1);
    atomicAdd(&h[vv.z >> 8], 1);
    atomicAdd(&h[vv.w >> 8], 1);
  }
  for (int k = (m4 << 2) + threadIdx.x; k < m; k += BLK)
    atomicAdd(&h[dst[base + k] >> 8], 1);
  __syncthreads();
  int* row = blockhist + (size_t)blockIdx.x * NBK;
  int sft = (blockIdx.x * 193) % NBK;   // stagger to decorrelate gcnt atomics
  for (int bb = threadIdx.x; bb < NBK; bb += BLK) {
    int b = bb + sft; if (b >= NBK) b -= NBK;
    int c = h[b];
    row[b] = c;
    if (c) atomicAdd(&gcnt[b], c);
  }
}

// exclusive scan of gcnt[NBK] -> gbase[NBK+1]; init gcur. single block, 1024 thr.
__global__ void k_scan(const int* __restrict__ gcnt, int* __restrict__ gbase,
                       int* __restrict__ gcur, int e) {
  __shared__ int s[1024];
  int t = threadIdx.x;
  int v = (t < NBK) ? gcnt[t] : 0;
  s[t] = v;
  __syncthreads();
  for (int d = 1; d < 1024; d <<= 1) {
    int u = (t >= d) ? s[t - d] : 0;
    __syncthreads();
    s[t] += u;
    __syncthreads();
  }
  if (t < NBK) { int ex = s[t] - v; gbase[t] = ex; gcur[t] = ex; }
  if (t == 0) gbase[NBK] = e;
}

// bin edges: load saved histogram, LDS counting-sort, coalesced write-out with
// direct pos->bucket lookup. Wave-shuffle scan (2 barriers).
__global__ void __launch_bounds__(BBLK) k_bin(const int* __restrict__ src,
                                              const int* __restrict__ dst, int e,
                                              int* __restrict__ gcur,
                                              const int* __restrict__ blockhist,
                                              unsigned* __restrict__ binned) {
  __shared__ int lcnt[NBK];        // histogram, then reused as scatter cursor
  __shared__ int loff[NBK + 1];
  __shared__ int lbase[NBK];
  __shared__ int wsum[8];
  __shared__ unsigned sorted[CHUNK];        // 24 KB
  __shared__ unsigned short bkt16[CHUNK];   // 12 KB
  int t = threadIdx.x;
  int base = blockIdx.x * CHUNK;
  int m = min(CHUNK, e - base);

  const int* row = blockhist + (size_t)blockIdx.x * NBK;
  for (int i = t; i < NBK; i += BBLK) lcnt[i] = row[i];
  __syncthreads();
  int b0 = 2 * t;
  int s0 = (b0 + 0 < NBK) ? lcnt[b0 + 0] : 0;
  int s1 = (b0 + 1 < NBK) ? lcnt[b0 + 1] : 0;
  int tsum = s0 + s1;
  // wave-shuffle inclusive scan of tsum over 512 threads
  int lane = t & 63, wid = t >> 6;
  int incl = tsum;
#pragma unroll
  for (int d = 1; d < 64; d <<= 1) {
    int u = __shfl_up(incl, d);
    if (lane >= d) incl += u;
  }
  if (lane == 63) wsum[wid] = incl;
  __syncthreads();
  if (t == 0) {
    int run = 0;
#pragma unroll
    for (int i = 0; i < 8; i++) { int tv = wsum[i]; wsum[i] = run; run += tv; }
  }
  __syncthreads();
  int ex = incl - tsum + wsum[wid];
  if (b0 + 0 < NBK) loff[b0 + 0] = ex;
  if (b0 + 1 < NBK) loff[b0 + 1] = ex + s0;
  if (t == 0) loff[NBK] = m;
  __syncthreads();
  int sft = (blockIdx.x * 193) % NBK;   // stagger to decorrelate gcur atomics
  for (int bb = t; bb < NBK; bb += BBLK) {
    int b = bb + sft; if (b >= NBK) b -= NBK;
    int c = lcnt[b];
    lbase[b] = c ? atomicAdd(&gcur[b], c) : 0;
  }
  __syncthreads();
  for (int b = t; b < NBK; b += BBLK) lcnt[b] = loff[b];
  __syncthreads();
  for (int k = t; k < m; k += BBLK) {
    int d = dst[base + k];
    int b = d >> 8;
    int dl = d & 255;
    int pos = atomicAdd(&lcnt[b], 1);
    sorted[pos] = (unsigned)src[base + k] | ((unsigned)dl << 18);
    bkt16[pos] = (unsigned short)b;
  }
  __syncthreads();
  for (int i = t; i < m; i += BBLK) {
    int b = bkt16[i];
    binned[lbase[b] + (i - loff[b])] = sorted[i];
  }
}

// fused: per-bucket 512-key counts (key = dl<<1 | src_half) -> deg2 + dinv ->
// hs1 = fp16((x@W1)*dinv), interleaved 32B rows. 4-deep unrolled count loop.
// NOTE: deg2 row is written for ALL t < NK2 in every bucket (incl. tail).
__global__ void __launch_bounds__(DBLK) k_ldeg_t1(const unsigned* __restrict__ binned,
                                                  const int* __restrict__ gbase,
                                                  const float* __restrict__ x,
                                                  const float* __restrict__ W1,
                                                  int* __restrict__ deg2,
                                                  float* __restrict__ dinv,
                                                  __half* __restrict__ hs1, int n) {
  __shared__ int cnt[2][NK2];      // 4 KB, dual banks to halve atomic contention
  __shared__ float w[160];
  int t = threadIdx.x;
  cnt[0][t] = 0;
  cnt[1][t] = 0;
  if (t < 160) w[t] = W1[t];
  __syncthreads();
  int b = blockIdx.x;
  int p0 = gbase[b], p1 = gbase[b + 1];
  int h = t >> 8;
#define KEYOF(u) ((int)(((u) >> 18) << 1) | (int)(((u) & 0x3FFFFu) >= (unsigned)HALF))
  int p = p0 + t;
  for (; p + 3 * DBLK < p1; p += 4 * DBLK) {
    unsigned u0 = binned[p];
    unsigned u1 = binned[p + DBLK];
    unsigned u2 = binned[p + 2 * DBLK];
    unsigned u3 = binned[p + 3 * DBLK];
    atomicAdd(&cnt[h][KEYOF(u0)], 1);
    atomicAdd(&cnt[h][KEYOF(u1)], 1);
    atomicAdd(&cnt[h][KEYOF(u2)], 1);
    atomicAdd(&cnt[h][KEYOF(u3)], 1);
  }
  for (; p < p1; p += DBLK) {
    unsigned u = binned[p];
    atomicAdd(&cnt[h][KEYOF(u)], 1);
  }
#undef KEYOF
  __syncthreads();
  deg2[(size_t)b * NK2 + t] = cnt[0][t] + cnt[1][t];   // always: full row
  if (t >= BW) return;
  int v = b * BW + t;
  if (v >= n) return;
  int dg = cnt[0][2 * t] + cnt[0][2 * t + 1] + cnt[1][2 * t] + cnt[1][2 * t + 1];
  float di = rsqrtf((float)dg + 1.0f);
  dinv[v] = di;
  float xi[10];
#pragma unroll
  for (int k = 0; k < 10; k++) xi[k] = x[(size_t)v * 10 + k];
  __half2 hv[8];
#pragma unroll
  for (int j = 0; j < 8; j++) {
    float acc0 = 0.f, acc1 = 0.f;
#pragma unroll
    for (int k = 0; k < 10; k++) {
      acc0 = fmaf(xi[k], w[k * 16 + 2 * j], acc0);
      acc1 = fmaf(xi[k], w[k * 16 + 2 * j + 1], acc1);
    }
    hv[j] = __floats2half2_rn(acc0 * di, acc1 * di);
  }
  float4* o = (float4*)(hs1 + (size_t)v * 16);
  o[0] = *(float4*)&hv[0];
  o[1] = *(float4*)&hv[4];
}

// FUSED layers 1+2, plain launch + manual grid barrier. FIX vs round 12: the
// spin polls with RELAXED agent loads (no cache-invalidate per poll — the
// round-12 667us pathology was acquire-polls continuously invalidating the
// XCD's L2 and destroying co-located blocks' hs1 residency). ONE acquire
// fence after the spin exits. Residency proof: VGPR<=64 (bounds 512,8) and
// LDS 39.7 KB both give 4 blk/CU; grid 782 <= 1024 slots => no deadlock.
__global__ void __launch_bounds__(ABLK, 8) k_aggf(unsigned* __restrict__ binned,
                                                  const int* __restrict__ gbase,
                                                  const int* __restrict__ deg2,
                                                  int* __restrict__ doff,
                                                  const __half* __restrict__ hs1,
                                                  const float* __restrict__ dinv,
                                                  const float* __restrict__ b1,
                                                  const float* __restrict__ W2,
                                                  const float* __restrict__ b2,
                                                  float* __restrict__ hs2,
                                                  float* __restrict__ out,
                                                  int* __restrict__ bar, int n) {
  __shared__ int cnt[NK2];          // counts -> scatter cursor
  __shared__ int off[NK2 + 1];
  __shared__ int sorted[CAP];       // 34.5 KB
  __shared__ int wsum[8];
  __shared__ float w2[32];
  __shared__ float sb1[16];
  int t = threadIdx.x;
  if (t < 32) w2[t] = W2[t];
  if (t >= 32 && t < 48) sb1[t - 32] = b1[t - 32];
  int bkt = blockIdx.x;
  int p0 = gbase[bkt], p1 = gbase[bkt + 1];
  const bool fast = (p1 - p0) <= CAP;   // single chunk: deg2 == per-chunk counts
  const int j = t >> 1;
  const int c = t & 1;
  const int lane = t & 63, wid = t >> 6;
  float acc[8];
#pragma unroll
  for (int q = 0; q < 8; q++) acc[q] = 0.f;

#define ACCR(R) { const __half2* h2_ = (const __half2*)&R; \
    float2 f0_ = __half22float2(h2_[0]); \
    float2 f1_ = __half22float2(h2_[1]); \
    float2 f2_ = __half22float2(h2_[2]); \
    float2 f3_ = __half22float2(h2_[3]); \
    acc[0] += f0_.x; acc[1] += f0_.y; acc[2] += f1_.x; acc[3] += f1_.y; \
    acc[4] += f2_.x; acc[5] += f2_.y; acc[6] += f3_.x; acc[7] += f3_.y; }

  int p = p0;
  int cidx = 0;
  while (p < p1) {
    int m = min(CAP, p1 - p);
    int myv;
    if (fast) {
      myv = deg2[(size_t)bkt * NK2 + t];
    } else {
      cnt[t] = 0;
      __syncthreads();
      for (int i = t; i < m; i += ABLK) {
        unsigned u = __builtin_nontemporal_load(&binned[p + i]);
        int key = (int)((u >> 18) << 1) | (int)((u & 0x3FFFFu) >= (unsigned)HALF);
        atomicAdd(&cnt[key], 1);
      }
      __syncthreads();
      myv = cnt[t];
    }
    // wave-shuffle exclusive scan of myv over 512 threads
    int incl = myv;
#pragma unroll
    for (int d = 1; d < 64; d <<= 1) {
      int u = __shfl_up(incl, d);
      if (lane >= d) incl += u;
    }
    if (lane == 63) wsum[wid] = incl;
    __syncthreads();
    if (t == 0) {
      int run = 0;
#pragma unroll
      for (int i = 0; i < 8; i++) { int tv = wsum[i]; wsum[i] = run; run += tv; }
    }
    __syncthreads();
    int ex = incl - myv + wsum[wid];
    off[t] = ex;
    if (t == NK2 - 1) off[NK2] = m;
    cnt[t] = ex;                    // scatter cursor
    __syncthreads();
    if (!fast && cidx < NCH && t <= BW)
      doff[((size_t)bkt * NCH + cidx) * (BW + 1) + t] = off[2 * t];
    for (int i = t; i < m; i += ABLK) {
      unsigned pk = __builtin_nontemporal_load(&binned[p + i]);
      int srcv = (int)(pk & 0x3FFFFu);
      int key = (int)((pk >> 18) << 1) | (int)(srcv >= HALF);
      int pos = atomicAdd(&cnt[key], 1);
      sorted[pos] = srcv;
    }
    __syncthreads();
    if (!fast) {
      // fallback only: persist dl-sorted srcs for the post-barrier chunk loop
      for (int i = t; i < m; i += ABLK)
        __builtin_nontemporal_store((unsigned)sorted[i], &binned[p + i]);
    }
    int iA0 = off[2 * j], iA1 = off[2 * j + 1], iB1 = off[2 * j + 2];
    // ---- phase A: src < HALF (hs1 lower 3.2 MB) ----
    int i = iA0;
    for (; i + 3 < iA1; i += 4) {
      int s0 = sorted[i + 0];
      int s1 = sorted[i + 1];
      int s2 = sorted[i + 2];
      int s3 = sorted[i + 3];
      float4 r0 = *(const float4*)(hs1 + (size_t)s0 * 16 + c * 8);
      float4 r1 = *(const float4*)(hs1 + (size_t)s1 * 16 + c * 8);
      float4 r2 = *(const float4*)(hs1 + (size_t)s2 * 16 + c * 8);
      float4 r3 = *(const float4*)(hs1 + (size_t)s3 * 16 + c * 8);
      ACCR(r0); ACCR(r1); ACCR(r2); ACCR(r3);
    }
    for (; i < iA1; i++) {
      float4 r = *(const float4*)(hs1 + (size_t)sorted[i] * 16 + c * 8);
      ACCR(r);
    }
    __syncthreads();   // phase alignment: block-wide working set = one half
    // ---- phase B: src >= HALF (hs1 upper 3.2 MB) ----
    for (; i + 3 < iB1; i += 4) {
      int s0 = sorted[i + 0];
      int s1 = sorted[i + 1];
      int s2 = sorted[i + 2];
      int s3 = sorted[i + 3];
      float4 r0 = *(const float4*)(hs1 + (size_t)s0 * 16 + c * 8);
      float4 r1 = *(const float4*)(hs1 + (size_t)s1 * 16 + c * 8);
      float4 r2 = *(const float4*)(hs1 + (size_t)s2 * 16 + c * 8);
      float4 r3 = *(const float4*)(hs1 + (size_t)s3 * 16 + c * 8);
      ACCR(r0); ACCR(r1); ACCR(r2); ACCR(r3);
    }
    for (; i < iB1; i++) {
      float4 r = *(const float4*)(hs1 + (size_t)sorted[i] * 16 + c * 8);
      ACCR(r);
    }
    __syncthreads();
    p += m;
    cidx++;
  }
#undef ACCR

  // ---- layer-1 epilogue: hs2[v] (both lanes keep the full h0/h1 and di) ----
  int v = bkt * BW + j;
  const bool own = (v < n);
  float di = 0.f, h0d = 0.f, h1d = 0.f;
  if (own) {
    di = dinv[v];
    float4 sf = *(const float4*)(hs1 + (size_t)v * 16 + c * 8);
    const __half2* sh = (const __half2*)&sf;
    float h0c = 0.f, h1c = 0.f;
#pragma unroll
    for (int q = 0; q < 4; q++) {
      float2 sv = __half22float2(sh[q]);
      int f0 = c * 8 + 2 * q;
      int f1 = f0 + 1;
      float a0 = fmaxf(fmaf(di, acc[2 * q + 0] + sv.x, sb1[f0]), 0.f);
      float a1 = fmaxf(fmaf(di, acc[2 * q + 1] + sv.y, sb1[f1]), 0.f);
      h0c = fmaf(a0, w2[f0 * 2 + 0], fmaf(a1, w2[f1 * 2 + 0], h0c));
      h1c = fmaf(a0, w2[f0 * 2 + 1], fmaf(a1, w2[f1 * 2 + 1], h1c));
    }
    float h0 = h0c + __shfl_xor(h0c, 1);
    float h1 = h1c + __shfl_xor(h1c, 1);
    h0d = h0 * di;
    h1d = h1 * di;
    if (c == 0) {
      hs2[(size_t)v * 2 + 0] = h0d;
      hs2[(size_t)v * 2 + 1] = h1d;
    }
  }

  // ---- manual grid barrier: RELAXED polls, single acquire fence after ----
  __threadfence();                  // release: hs2 writes visible device-wide
  __syncthreads();
  if (t == 0) {
    __hip_atomic_fetch_add(bar, 1, __ATOMIC_RELEASE, __HIP_MEMORY_SCOPE_AGENT);
    while (__hip_atomic_load(bar, __ATOMIC_RELAXED, __HIP_MEMORY_SCOPE_AGENT)
           < (int)gridDim.x)
      __builtin_amdgcn_s_sleep(64);
  }
  __syncthreads();
  __threadfence();                  // single acquire: invalidate stale hs2 once

  // ---- layer 2: gather hs2 over this dst's dl-segment (LDS-resident) ----
  float a0 = 0.f, a1 = 0.f;
  if (fast) {
    int i0 = off[2 * j], i1 = off[2 * j + 2];
    int i = i0 + c;
    for (; i + 6 < i1; i += 8) {
      int s0 = sorted[i + 0];
      int s1 = sorted[i + 2];
      int s2 = sorted[i + 4];
      int s3 = sorted[i + 6];
      float2 m0 = *(const float2*)(hs2 + (size_t)s0 * 2);
      float2 m1 = *(const float2*)(hs2 + (size_t)s1 * 2);
      float2 m2 = *(const float2*)(hs2 + (size_t)s2 * 2);
      float2 m3 = *(const float2*)(hs2 + (size_t)s3 * 2);
      a0 += m0.x + m1.x + m2.x + m3.x;
      a1 += m0.y + m1.y + m2.y + m3.y;
    }
    for (; i < i1; i += 2) {
      float2 m = *(const float2*)(hs2 + (size_t)sorted[i] * 2);
      a0 += m.x;
      a1 += m.y;
    }
  } else {
    int cidx2 = 0;
    for (int pp = p0; pp < p1; pp += CAP, cidx2++) {
      const int* row = doff + ((size_t)bkt * NCH + cidx2) * (BW + 1);
      int i0 = row[j], i1 = row[j + 1];
      const unsigned* bp = binned + pp;
      int i = i0 + c;
      for (; i + 6 < i1; i += 8) {
        int s0 = bp[i + 0];
        int s1 = bp[i + 2];
        int s2 = bp[i + 4];
        int s3 = bp[i + 6];
        float2 m0 = *(const float2*)(hs2 + (size_t)s0 * 2);
        float2 m1 = *(const float2*)(hs2 + (size_t)s1 * 2);
        float2 m2 = *(const float2*)(hs2 + (size_t)s2 * 2);
        float2 m3 = *(const float2*)(hs2 + (size_t)s3 * 2);
        a0 += m0.x + m1.x + m2.x + m3.x;
        a1 += m0.y + m1.y + m2.y + m3.y;
      }
      for (; i < i1; i += 2) {
        float2 m = *(const float2*)(hs2 + (size_t)bp[i] * 2);
        a0 += m.x;
        a1 += m.y;
      }
    }
  }
  a0 += __shfl_xor(a0, 1);
  a1 += __shfl_xor(a1, 1);
  if (c == 0 && own) {
    out[(size_t)v * 2 + 0] = fmaf(di, a0 + h0d, b2[0]);
    out[(size_t)v * 2 + 1] = fmaf(di, a1 + h1d, b2[1]);
  }
}

extern "C" void kernel_launch(void* const* d_in, const int* in_sizes, int n_in,
                              void* d_out, int out_size, void* d_ws, size_t ws_size,
                              hipStream_t stream) {
  const float* x  = (const float*)d_in[0];
  const int*   ei = (const int*)d_in[1];
  const float* W1 = (const float*)d_in[2];
  const float* b1 = (const float*)d_in[3];
  const float* W2 = (const float*)d_in[4];
  const float* b2 = (const float*)d_in[5];
  float* out = (float*)d_out;

  const int n = in_sizes[0] / 10;   // 200000
  const int e = in_sizes[1] / 2;    // 6400000
  const int* src = ei;
  const int* dst = ei + e;

  int gC = (e + CHUNK - 1) / CHUNK;   // 1042 binning blocks

  // workspace layout (~42 MB). bar sits right after gcnt: one memset zeroes both.
  char* ws = (char*)d_ws;
  int*      gcnt      = (int*)ws;      ws += (size_t)NBK * 4;
  int*      bar       = (int*)ws;      ws += 4;
  int*      gbase     = (int*)ws;      ws += ((size_t)NBK + 1) * 4;
  int*      gcur      = (int*)ws;      ws += (size_t)NBK * 4;
  int*      deg2      = (int*)ws;      ws += (size_t)NBK * NK2 * 4;
  int*      doff      = (int*)ws;      ws += (size_t)NBK * NCH * (BW + 1) * 4;
  int*      blockhist = (int*)ws;      ws += (size_t)gC * NBK * 4;
  unsigned* binned    = (unsigned*)ws; ws += (size_t)e * 4;
  float*    dinv      = (float*)ws;    ws += (size_t)n * 4;
  __half*   hs1       = (__half*)ws;   ws += (size_t)NPAD * 16 * 2;
  float*    hs2       = (float*)ws;    ws += (size_t)n * 2 * 4;

  hipMemsetAsync(gcnt, 0, ((size_t)NBK + 1) * 4, stream);
  k_hist<<<gC, BLK, 0, stream>>>(dst, e, gcnt, blockhist);
  k_scan<<<1, 1024, 0, stream>>>(gcnt, gbase, gcur, e);
  k_bin<<<gC, BBLK, 0, stream>>>(src, dst, e, gcur, blockhist, binned);
  k_ldeg_t1<<<NBK, DBLK, 0, stream>>>(binned, gbase, x, W1, deg2, dinv, hs1, n);
  k_aggf<<<NBK, ABLK, 0, stream>>>(binned, gbase, deg2, doff, hs1, dinv, b1, W2,
                                   b2, hs2, out, bar, n);
}

// Round 14
// 293.265 us; speedup vs baseline: 2.8973x; 2.0640x over previous
//
#include <hip/hip_runtime.h>
#include <hip/hip_fp16.h>

#define BLK 256
#define BBLK 512             // k_bin / k_agg2 block
#define ABLK 512             // agg1 block: 256 lane-pairs
#define DBLK 512             // ldeg_t1 block (quad LDS counter banks)
#define NBK 782              // dst buckets of 256 nodes (782*256 >= 200000)
#define BW 256               // nodes per bucket (dl fits 8 bits)
#define NK2 512              // sort keys: (dl<<1) | src_half
#define NPAD (NBK * BW)      // padded node count (200192)
#define HALF (NPAD / 2)      // src-half threshold: each hs1 half = 3.2 MB (L2-fits)
#define CAP 8960             // edges sorted per chunk in agg1 (max bucket ~8500; ~40 KB LDS -> 4 blk/CU)
#define NCH 3                // max chunks per bucket tracked in doff (fallback only)
#define CHUNK 6144           // edges per binning block -> 1042 blocks

// ---------- bucket build ----------

// per-block histogram -> blockhist row (persisted) + global bucket counts.
__global__ void k_hist(const int* __restrict__ dst, int e, int* __restrict__ gcnt,
                       int* __restrict__ blockhist) {
  __shared__ int h[NBK];
  for (int i = threadIdx.x; i < NBK; i += BLK) h[i] = 0;
  __syncthreads();
  int base = blockIdx.x * CHUNK;
  int m = min(CHUNK, e - base);
  int m4 = m >> 2;
  const int4* d4 = (const int4*)(dst + base);
  for (int k = threadIdx.x; k < m4; k += BLK) {
    int4 vv = d4[k];
    atomicAdd(&h[vv.x >> 8], 1);
    atomicAdd(&h[vv.y >> 8], 1);
    atomicAdd(&h[vv.z >> 8], 1);
    atomicAdd(&h[vv.w >> 8], 1);
  }
  for (int k = (m4 << 2) + threadIdx.x; k < m; k += BLK)
    atomicAdd(&h[dst[base + k] >> 8], 1);
  __syncthreads();
  int* row = blockhist + (size_t)blockIdx.x * NBK;
  int sft = (blockIdx.x * 193) % NBK;   // stagger to decorrelate gcnt atomics
  for (int bb = threadIdx.x; bb < NBK; bb += BLK) {
    int b = bb + sft; if (b >= NBK) b -= NBK;
    int c = h[b];
    row[b] = c;
    if (c) atomicAdd(&gcnt[b], c);
  }
}

// exclusive scan of gcnt[NBK] -> gbase[NBK+1]; init gcur. single block, 1024 thr.
__global__ void k_scan(const int* __restrict__ gcnt, int* __restrict__ gbase,
                       int* __restrict__ gcur, int e) {
  __shared__ int s[1024];
  int t = threadIdx.x;
  int v = (t < NBK) ? gcnt[t] : 0;
  s[t] = v;
  __syncthreads();
  for (int d = 1; d < 1024; d <<= 1) {
    int u = (t >= d) ? s[t - d] : 0;
    __syncthreads();
    s[t] += u;
    __syncthreads();
  }
  if (t < NBK) { int ex = s[t] - v; gbase[t] = ex; gcur[t] = ex; }
  if (t == 0) gbase[NBK] = e;
}

// bin edges: load saved histogram, LDS counting-sort, coalesced write-out with
// direct pos->bucket lookup. Wave-shuffle scan (2 barriers).
__global__ void __launch_bounds__(BBLK) k_bin(const int* __restrict__ src,
                                              const int* __restrict__ dst, int e,
                                              int* __restrict__ gcur,
                                              const int* __restrict__ blockhist,
                                              unsigned* __restrict__ binned) {
  __shared__ int lcnt[NBK];        // histogram, then reused as scatter cursor
  __shared__ int loff[NBK + 1];
  __shared__ int lbase[NBK];
  __shared__ int wsum[8];
  __shared__ unsigned sorted[CHUNK];        // 24 KB
  __shared__ unsigned short bkt16[CHUNK];   // 12 KB
  int t = threadIdx.x;
  int base = blockIdx.x * CHUNK;
  int m = min(CHUNK, e - base);

  const int* row = blockhist + (size_t)blockIdx.x * NBK;
  for (int i = t; i < NBK; i += BBLK) lcnt[i] = row[i];
  __syncthreads();
  int b0 = 2 * t;
  int s0 = (b0 + 0 < NBK) ? lcnt[b0 + 0] : 0;
  int s1 = (b0 + 1 < NBK) ? lcnt[b0 + 1] : 0;
  int tsum = s0 + s1;
  // wave-shuffle inclusive scan of tsum over 512 threads
  int lane = t & 63, wid = t >> 6;
  int incl = tsum;
#pragma unroll
  for (int d = 1; d < 64; d <<= 1) {
    int u = __shfl_up(incl, d);
    if (lane >= d) incl += u;
  }
  if (lane == 63) wsum[wid] = incl;
  __syncthreads();
  if (t == 0) {
    int run = 0;
#pragma unroll
    for (int i = 0; i < 8; i++) { int tv = wsum[i]; wsum[i] = run; run += tv; }
  }
  __syncthreads();
  int ex = incl - tsum + wsum[wid];
  if (b0 + 0 < NBK) loff[b0 + 0] = ex;
  if (b0 + 1 < NBK) loff[b0 + 1] = ex + s0;
  if (t == 0) loff[NBK] = m;
  __syncthreads();
  int sft = (blockIdx.x * 193) % NBK;   // stagger to decorrelate gcur atomics
  for (int bb = t; bb < NBK; bb += BBLK) {
    int b = bb + sft; if (b >= NBK) b -= NBK;
    int c = lcnt[b];
    lbase[b] = c ? atomicAdd(&gcur[b], c) : 0;
  }
  __syncthreads();
  for (int b = t; b < NBK; b += BBLK) lcnt[b] = loff[b];
  __syncthreads();
  for (int k = t; k < m; k += BBLK) {
    int d = dst[base + k];
    int b = d >> 8;
    int dl = d & 255;
    int pos = atomicAdd(&lcnt[b], 1);
    sorted[pos] = (unsigned)src[base + k] | ((unsigned)dl << 18);
    bkt16[pos] = (unsigned short)b;
  }
  __syncthreads();
  for (int i = t; i < m; i += BBLK) {
    int b = bkt16[i];
    binned[lbase[b] + (i - loff[b])] = sorted[i];
  }
}

// fused: per-bucket 512-key counts (key = dl<<1 | src_half) -> deg2 + dinv ->
// hs1 = fp16((x@W1)*dinv), interleaved 32B rows. 4-deep unrolled count loop.
// NEW: QUAD LDS counter banks (8 KB) — halves same-bank atomic serialization
// vs dual banks on the 6.4M-edge count pass.
// NOTE: deg2 row is written for ALL t < NK2 in every bucket (incl. tail).
__global__ void __launch_bounds__(DBLK) k_ldeg_t1(const unsigned* __restrict__ binned,
                                                  const int* __restrict__ gbase,
                                                  const float* __restrict__ x,
                                                  const float* __restrict__ W1,
                                                  int* __restrict__ deg2,
                                                  float* __restrict__ dinv,
                                                  __half* __restrict__ hs1, int n) {
  __shared__ int cnt[4][NK2];      // 8 KB, quad banks
  __shared__ float w[160];
  int t = threadIdx.x;
  cnt[0][t] = 0;
  cnt[1][t] = 0;
  cnt[2][t] = 0;
  cnt[3][t] = 0;
  if (t < 160) w[t] = W1[t];
  __syncthreads();
  int b = blockIdx.x;
  int p0 = gbase[b], p1 = gbase[b + 1];
  int h = t >> 7;                  // 4 banks of 128 threads
#define KEYOF(u) ((int)(((u) >> 18) << 1) | (int)(((u) & 0x3FFFFu) >= (unsigned)HALF))
  int p = p0 + t;
  for (; p + 3 * DBLK < p1; p += 4 * DBLK) {
    unsigned u0 = binned[p];
    unsigned u1 = binned[p + DBLK];
    unsigned u2 = binned[p + 2 * DBLK];
    unsigned u3 = binned[p + 3 * DBLK];
    atomicAdd(&cnt[h][KEYOF(u0)], 1);
    atomicAdd(&cnt[h][KEYOF(u1)], 1);
    atomicAdd(&cnt[h][KEYOF(u2)], 1);
    atomicAdd(&cnt[h][KEYOF(u3)], 1);
  }
  for (; p < p1; p += DBLK) {
    unsigned u = binned[p];
    atomicAdd(&cnt[h][KEYOF(u)], 1);
  }
#undef KEYOF
  __syncthreads();
  deg2[(size_t)b * NK2 + t] = cnt[0][t] + cnt[1][t] + cnt[2][t] + cnt[3][t];
  if (t >= BW) return;
  int v = b * BW + t;
  if (v >= n) return;
  int dg = cnt[0][2 * t] + cnt[0][2 * t + 1] + cnt[1][2 * t] + cnt[1][2 * t + 1]
         + cnt[2][2 * t] + cnt[2][2 * t + 1] + cnt[3][2 * t] + cnt[3][2 * t + 1];
  float di = rsqrtf((float)dg + 1.0f);
  dinv[v] = di;
  float xi[10];
#pragma unroll
  for (int k = 0; k < 10; k++) xi[k] = x[(size_t)v * 10 + k];
  __half2 hv[8];
#pragma unroll
  for (int j = 0; j < 8; j++) {
    float acc0 = 0.f, acc1 = 0.f;
#pragma unroll
    for (int k = 0; k < 10; k++) {
      acc0 = fmaf(xi[k], w[k * 16 + 2 * j], acc0);
      acc1 = fmaf(xi[k], w[k * 16 + 2 * j + 1], acc1);
    }
    hv[j] = __floats2half2_rn(acc0 * di, acc1 * di);
  }
  float4* o = (float4*)(hs1 + (size_t)v * 16);
  o[0] = *(float4*)&hv[0];
  o[1] = *(float4*)&hv[4];
}

// layer-1 aggregation: ROUND-10 structure (proven 73.5 us) — 512-key
// counting-sort (dl<<1|half), dst-owned lane-pair gather, two src-half phases
// (L2-resident), wave-shuffle scan. Fusion with layer-2 was tried (rounds
// 11-13) and is structurally net-negative: cross-XCD hs2 visibility needs
// per-block L2 invalidates (buffer_inv from agent fences), which destroy the
// hs1/hs2 L2 residency this kernel depends on (FETCH-invisible L3 refetches).
__global__ void __launch_bounds__(ABLK) k_agg1s(unsigned* __restrict__ binned,
                                                const int* __restrict__ gbase,
                                                const int* __restrict__ deg2,
                                                int* __restrict__ doff,
                                                const __half* __restrict__ hs1,
                                                const float* __restrict__ dinv,
                                                const float* __restrict__ b1,
                                                const float* __restrict__ W2,
                                                float* __restrict__ hs2, int n) {
  __shared__ int cnt[NK2];          // counts -> scatter cursor
  __shared__ int off[NK2 + 1];
  __shared__ int sorted[CAP];       // 35 KB
  __shared__ int wsum[8];
  __shared__ float w2[32];
  __shared__ float sb1[16];
  int t = threadIdx.x;
  if (t < 32) w2[t] = W2[t];
  if (t >= 32 && t < 48) sb1[t - 32] = b1[t - 32];
  int bkt = blockIdx.x;
  int p0 = gbase[bkt], p1 = gbase[bkt + 1];
  const bool fast = (p1 - p0) <= CAP;   // single chunk: deg2 == per-chunk counts
  const int j = t >> 1;
  const int c = t & 1;
  const int lane = t & 63, wid = t >> 6;
  float acc[8];
#pragma unroll
  for (int q = 0; q < 8; q++) acc[q] = 0.f;

#define ACCR(R) { const __half2* h2_ = (const __half2*)&R; \
    float2 f0_ = __half22float2(h2_[0]); \
    float2 f1_ = __half22float2(h2_[1]); \
    float2 f2_ = __half22float2(h2_[2]); \
    float2 f3_ = __half22float2(h2_[3]); \
    acc[0] += f0_.x; acc[1] += f0_.y; acc[2] += f1_.x; acc[3] += f1_.y; \
    acc[4] += f2_.x; acc[5] += f2_.y; acc[6] += f3_.x; acc[7] += f3_.y; }

  int p = p0;
  int cidx = 0;
  while (p < p1) {
    int m = min(CAP, p1 - p);
    int myv;
    if (fast) {
      myv = deg2[(size_t)bkt * NK2 + t];
    } else {
      cnt[t] = 0;
      __syncthreads();
      for (int i = t; i < m; i += ABLK) {
        unsigned u = __builtin_nontemporal_load(&binned[p + i]);
        int key = (int)((u >> 18) << 1) | (int)((u & 0x3FFFFu) >= (unsigned)HALF);
        atomicAdd(&cnt[key], 1);
      }
      __syncthreads();
      myv = cnt[t];
    }
    // wave-shuffle exclusive scan of myv over 512 threads
    int incl = myv;
#pragma unroll
    for (int d = 1; d < 64; d <<= 1) {
      int u = __shfl_up(incl, d);
      if (lane >= d) incl += u;
    }
    if (lane == 63) wsum[wid] = incl;
    __syncthreads();
    if (t == 0) {
      int run = 0;
#pragma unroll
      for (int i = 0; i < 8; i++) { int tv = wsum[i]; wsum[i] = run; run += tv; }
    }
    __syncthreads();
    int ex = incl - myv + wsum[wid];
    off[t] = ex;
    if (t == NK2 - 1) off[NK2] = m;
    cnt[t] = ex;                    // scatter cursor
    __syncthreads();
    if (cidx < NCH && t <= BW) doff[((size_t)bkt * NCH + cidx) * (BW + 1) + t] = off[2 * t];
    for (int i = t; i < m; i += ABLK) {
      unsigned pk = __builtin_nontemporal_load(&binned[p + i]);
      int srcv = (int)(pk & 0x3FFFFu);
      int key = (int)((pk >> 18) << 1) | (int)(srcv >= HALF);
      int pos = atomicAdd(&cnt[key], 1);
      sorted[pos] = srcv;
    }
    __syncthreads();
    // persist: (dl,half)-sorted srcs back into binned (nt) for k_agg2
    for (int i = t; i < m; i += ABLK)
      __builtin_nontemporal_store((unsigned)sorted[i], &binned[p + i]);
    int iA0 = off[2 * j], iA1 = off[2 * j + 1], iB1 = off[2 * j + 2];
    // ---- phase A: src < HALF (hs1 lower 3.2 MB) ----
    int i = iA0;
    for (; i + 3 < iA1; i += 4) {
      int s0 = sorted[i + 0];
      int s1 = sorted[i + 1];
      int s2 = sorted[i + 2];
      int s3 = sorted[i + 3];
      float4 r0 = *(const float4*)(hs1 + (size_t)s0 * 16 + c * 8);
      float4 r1 = *(const float4*)(hs1 + (size_t)s1 * 16 + c * 8);
      float4 r2 = *(const float4*)(hs1 + (size_t)s2 * 16 + c * 8);
      float4 r3 = *(const float4*)(hs1 + (size_t)s3 * 16 + c * 8);
      ACCR(r0); ACCR(r1); ACCR(r2); ACCR(r3);
    }
    for (; i < iA1; i++) {
      float4 r = *(const float4*)(hs1 + (size_t)sorted[i] * 16 + c * 8);
      ACCR(r);
    }
    __syncthreads();   // phase alignment: block-wide working set = one half
    // ---- phase B: src >= HALF (hs1 upper 3.2 MB) ----
    for (; i + 3 < iB1; i += 4) {
      int s0 = sorted[i + 0];
      int s1 = sorted[i + 1];
      int s2 = sorted[i + 2];
      int s3 = sorted[i + 3];
      float4 r0 = *(const float4*)(hs1 + (size_t)s0 * 16 + c * 8);
      float4 r1 = *(const float4*)(hs1 + (size_t)s1 * 16 + c * 8);
      float4 r2 = *(const float4*)(hs1 + (size_t)s2 * 16 + c * 8);
      float4 r3 = *(const float4*)(hs1 + (size_t)s3 * 16 + c * 8);
      ACCR(r0); ACCR(r1); ACCR(r2); ACCR(r3);
    }
    for (; i < iB1; i++) {
      float4 r = *(const float4*)(hs1 + (size_t)sorted[i] * 16 + c * 8);
      ACCR(r);
    }
    __syncthreads();
    p += m;
    cidx++;
  }
#undef ACCR

  int v = bkt * BW + j;
  if (v < n) {
    float di = dinv[v];
    float4 sf = *(const float4*)(hs1 + (size_t)v * 16 + c * 8);
    const __half2* sh = (const __half2*)&sf;
    float h0c = 0.f, h1c = 0.f;
#pragma unroll
    for (int q = 0; q < 4; q++) {
      float2 sv = __half22float2(sh[q]);
      int f0 = c * 8 + 2 * q;
      int f1 = f0 + 1;
      float a0 = fmaxf(fmaf(di, acc[2 * q + 0] + sv.x, sb1[f0]), 0.f);
      float a1 = fmaxf(fmaf(di, acc[2 * q + 1] + sv.y, sb1[f1]), 0.f);
      h0c = fmaf(a0, w2[f0 * 2 + 0], fmaf(a1, w2[f1 * 2 + 0], h0c));
      h1c = fmaf(a0, w2[f0 * 2 + 1], fmaf(a1, w2[f1 * 2 + 1], h1c));
    }
    float h0 = h0c + __shfl_xor(h0c, 1);
    float h1 = h1c + __shfl_xor(h1c, 1);
    if (c == 0) {
      hs2[(size_t)v * 2 + 0] = h0 * di;
      hs2[(size_t)v * 2 + 1] = h1 * di;
    }
  }
}

// layer-2 aggregate + output: ZERO atomics. Lane-OCT per dst — 8 lanes stride
// the dl-sorted segment by 8 (32 loads in flight per dst). 64 dsts per block,
// grid NBK*4. Reduce via shfl_xor 1,2,4 within the 8-lane group.
__global__ void __launch_bounds__(BBLK) k_agg2(const unsigned* __restrict__ binned,
                                               const int* __restrict__ gbase,
                                               const int* __restrict__ doff,
                                               const float* __restrict__ hs2,
                                               const float* __restrict__ dinv,
                                               const float* __restrict__ b2,
                                               float* __restrict__ out, int n) {
  int t = threadIdx.x;
  int bkt = blockIdx.x >> 2;
  int j = (t >> 3) + ((blockIdx.x & 3) << 6);   // dst-local in [0,256)
  int c = t & 7;
  int p0 = gbase[bkt], p1 = gbase[bkt + 1];
  float a0 = 0.f, a1 = 0.f;
  int cidx = 0;
  for (int p = p0; p < p1; p += CAP, cidx++) {
    const int* row = doff + ((size_t)bkt * NCH + cidx) * (BW + 1);
    int i0 = row[j], i1 = row[j + 1];
    const unsigned* bp = binned + p;
    int i = i0 + c;
    for (; i + 24 < i1; i += 32) {
      int s0 = bp[i + 0];
      int s1 = bp[i + 8];
      int s2 = bp[i + 16];
      int s3 = bp[i + 24];
      float2 m0 = *(const float2*)(hs2 + (size_t)s0 * 2);
      float2 m1 = *(const float2*)(hs2 + (size_t)s1 * 2);
      float2 m2 = *(const float2*)(hs2 + (size_t)s2 * 2);
      float2 m3 = *(const float2*)(hs2 + (size_t)s3 * 2);
      a0 += m0.x + m1.x + m2.x + m3.x;
      a1 += m0.y + m1.y + m2.y + m3.y;
    }
    for (; i < i1; i += 8) {
      float2 m = *(const float2*)(hs2 + (size_t)bp[i] * 2);
      a0 += m.x;
      a1 += m.y;
    }
  }
  a0 += __shfl_xor(a0, 1);
  a0 += __shfl_xor(a0, 2);
  a0 += __shfl_xor(a0, 4);
  a1 += __shfl_xor(a1, 1);
  a1 += __shfl_xor(a1, 2);
  a1 += __shfl_xor(a1, 4);
  int v = bkt * BW + j;
  if (c == 0 && v < n) {
    float di = dinv[v];
    out[(size_t)v * 2 + 0] = fmaf(di, a0 + hs2[(size_t)v * 2 + 0], b2[0]);
    out[(size_t)v * 2 + 1] = fmaf(di, a1 + hs2[(size_t)v * 2 + 1], b2[1]);
  }
}

extern "C" void kernel_launch(void* const* d_in, const int* in_sizes, int n_in,
                              void* d_out, int out_size, void* d_ws, size_t ws_size,
                              hipStream_t stream) {
  const float* x  = (const float*)d_in[0];
  const int*   ei = (const int*)d_in[1];
  const float* W1 = (const float*)d_in[2];
  const float* b1 = (const float*)d_in[3];
  const float* W2 = (const float*)d_in[4];
  const float* b2 = (const float*)d_in[5];
  float* out = (float*)d_out;

  const int n = in_sizes[0] / 10;   // 200000
  const int e = in_sizes[1] / 2;    // 6400000
  const int* src = ei;
  const int* dst = ei + e;

  int gC = (e + CHUNK - 1) / CHUNK;   // 1042 binning blocks

  // workspace layout (~42 MB)
  char* ws = (char*)d_ws;
  int*      gcnt      = (int*)ws;      ws += (size_t)NBK * 4;
  int*      gbase     = (int*)ws;      ws += ((size_t)NBK + 1) * 4;
  int*      gcur      = (int*)ws;      ws += (size_t)NBK * 4;
  int*      deg2      = (int*)ws;      ws += (size_t)NBK * NK2 * 4;
  int*      doff      = (int*)ws;      ws += (size_t)NBK * NCH * (BW + 1) * 4;
  int*      blockhist = (int*)ws;      ws += (size_t)gC * NBK * 4;
  unsigned* binned    = (unsigned*)ws; ws += (size_t)e * 4;
  float*    dinv      = (float*)ws;    ws += (size_t)n * 4;
  __half*   hs1       = (__half*)ws;   ws += (size_t)NPAD * 16 * 2;
  float*    hs2       = (float*)ws;    ws += (size_t)n * 2 * 4;

  hipMemsetAsync(gcnt, 0, (size_t)NBK * 4, stream);
  k_hist<<<gC, BLK, 0, stream>>>(dst, e, gcnt, blockhist);
  k_scan<<<1, 1024, 0, stream>>>(gcnt, gbase, gcur, e);
  k_bin<<<gC, BBLK, 0, stream>>>(src, dst, e, gcur, blockhist, binned);
  k_ldeg_t1<<<NBK, DBLK, 0, stream>>>(binned, gbase, x, W1, deg2, dinv, hs1, n);
  k_agg1s<<<NBK, ABLK, 0, stream>>>(binned, gbase, deg2, doff, hs1, dinv, b1, W2, hs2, n);
  k_agg2<<<NBK * 4, BBLK, 0, stream>>>(binned, gbase, doff, hs2, dinv, b2, out, n);
}